// Round 2
// baseline (145.762 us; speedup 1.0000x reference)
//
#include <hip/hip_runtime.h>

#define NB   4      // batch
#define CO   16     // out channels
#define PH   7
#define PW   7
#define SR   2
#define HH   80
#define WW   80
#define NROI 512
#define NOUT (NROI*CO*PH*PW)

// 8-byte vector with 4-byte alignment: lets the compiler emit a single
// global_load_dwordx2 (gfx9+ supports unaligned global access); worst case it
// splits into 2 dwords = parity with the old code.
typedef float f2v __attribute__((ext_vector_type(2), aligned(4)));

__global__ __launch_bounds__(256) void psroi_align_kernel(
    const float* __restrict__ feat,   // [B, CO*PH*PW, H, W]
    const float* __restrict__ rois,   // [N, 5]
    float* __restrict__ out)          // [N, CO, PH, PW]
{
    int idx = blockIdx.x * blockDim.x + threadIdx.x;
    if (idx >= NOUT) return;

    int j = idx % PW;
    int i = (idx / PW) % PH;
    int c = (idx / (PW * PH)) % CO;
    int n = idx / (PW * PH * CO);

    const float* r = rois + n * 5;
    float rb = r[0];
    float x1 = r[1] * (float)WW;
    float y1 = r[2] * (float)HH;
    float x2 = r[3] * (float)WW;
    float y2 = r[4] * (float)HH;
    int b = (int)rb;

    float roi_h = fmaxf(y2 - y1, 0.1f);
    float roi_w = fmaxf(x2 - x1, 0.1f);
    float bin_h = roi_h * (1.0f / PH);
    float bin_w = roi_w * (1.0f / PW);

    // position-sensitive plane: channel = c*PH*PW + i*PW + j
    const float* plane = feat + ((size_t)b * (CO * PH * PW) + (size_t)(c * PH * PW + i * PW + j)) * (HH * WW);

    float acc = 0.0f;
    #pragma unroll
    for (int sy = 0; sy < SR; ++sy) {
        float ys = y1 + (float)i * bin_h + ((float)sy + 0.5f) * bin_h / (float)SR;
        bool ymask = (ys >= -1.0f) && (ys <= (float)HH);
        float yc = fminf(fmaxf(ys, 0.0f), (float)(HH - 1));
        int   y0 = (int)floorf(yc);
        int   y1i = min(y0 + 1, HH - 1);
        float ly = yc - (float)y0;
        float hy = 1.0f - ly;

        #pragma unroll
        for (int sx = 0; sx < SR; ++sx) {
            float xs = x1 + (float)j * bin_w + ((float)sx + 0.5f) * bin_w / (float)SR;
            bool xmask = (xs >= -1.0f) && (xs <= (float)WW);
            float xc = fminf(fmaxf(xs, 0.0f), (float)(WW - 1));
            int   x0 = (int)floorf(xc);
            float lx = xc - (float)x0;
            float hx = 1.0f - lx;

            // Fused x-pair load. x0c = min(x0, 78); if x0 == 79 then lx == 0,
            // so using t.y (pixel 79) for both taps is exact.
            int x0c = min(x0, WW - 2);
            bool shifted = (x0 != x0c);

            f2v t = *(const f2v*)(plane + y0  * WW + x0c);
            f2v bt = *(const f2v*)(plane + y1i * WW + x0c);

            float v00 = shifted ? t.y  : t.x;
            float v01 = t.y;
            float v10 = shifted ? bt.y : bt.x;
            float v11 = bt.y;

            float vtop = v00 * hx + v01 * lx;
            float vbot = v10 * hx + v11 * lx;
            float v = vtop * hy + vbot * ly;

            if (ymask && xmask) acc += v;
        }
    }

    out[idx] = acc * 0.25f;
}

extern "C" void kernel_launch(void* const* d_in, const int* in_sizes, int n_in,
                              void* d_out, int out_size, void* d_ws, size_t ws_size,
                              hipStream_t stream)
{
    const float* feat = (const float*)d_in[0];
    const float* rois = (const float*)d_in[1];
    float* out = (float*)d_out;

    int total = NOUT;
    int block = 256;
    int grid = (total + block - 1) / block;
    psroi_align_kernel<<<grid, block, 0, stream>>>(feat, rois, out);
}

// Round 3
// 129.295 us; speedup vs baseline: 1.1274x; 1.1274x over previous
//
#include <hip/hip_runtime.h>

#define NB   4      // batch
#define CO   16     // out channels
#define PH   7
#define PW   7
#define SR   2
#define HH   80
#define WW   80
#define NROI 512
#define CIJ  (CO*PH*PW)   // 784

typedef float f2v __attribute__((ext_vector_type(2), aligned(4)));
typedef float f4v __attribute__((ext_vector_type(4), aligned(4)));

// Grid: 784 blocks, one per (c,i,j) plane-position. Block: 512 threads, one
// per ROI. All lanes of a wave gather from the same 4 planes (one per batch,
// ~102 KB) -> L1/L2 line reuse across ROIs instead of 64-way plane scatter.
__global__ __launch_bounds__(512) void psroi_align_kernel(
    const float* __restrict__ feat,   // [B, CO*PH*PW, H, W]
    const float* __restrict__ rois,   // [N, 5]
    float* __restrict__ out)          // [N, CO, PH, PW]
{
    int cij = blockIdx.x;             // 0..783 == c*49 + i*7 + j
    int rem = cij % (PH * PW);
    int i = rem / PW;
    int j = rem % PW;
    int n = threadIdx.x;              // 0..511

    f4v r4 = *(const f4v*)(rois + n * 5);   // b, x1, y1, x2
    float r5 = rois[n * 5 + 4];             // y2
    int   b  = (int)r4.x;
    float x1 = r4.y * (float)WW;
    float y1 = r4.z * (float)HH;
    float x2 = r4.w * (float)WW;
    float y2 = r5   * (float)HH;

    float roi_h = fmaxf(y2 - y1, 0.1f);
    float roi_w = fmaxf(x2 - x1, 0.1f);
    float bin_h = roi_h * (1.0f / PH);
    float bin_w = roi_w * (1.0f / PW);

    const float* plane = feat + ((size_t)b * CIJ + (size_t)cij) * (HH * WW);

    float acc = 0.0f;
    #pragma unroll
    for (int sy = 0; sy < SR; ++sy) {
        float ys = y1 + (float)i * bin_h + ((float)sy + 0.5f) * bin_h / (float)SR;
        bool ymask = (ys >= -1.0f) && (ys <= (float)HH);
        float yc = fminf(fmaxf(ys, 0.0f), (float)(HH - 1));
        int   y0 = (int)floorf(yc);
        int   y1i = min(y0 + 1, HH - 1);
        float ly = yc - (float)y0;
        float hy = 1.0f - ly;

        #pragma unroll
        for (int sx = 0; sx < SR; ++sx) {
            float xs = x1 + (float)j * bin_w + ((float)sx + 0.5f) * bin_w / (float)SR;
            bool xmask = (xs >= -1.0f) && (xs <= (float)WW);
            float xc = fminf(fmaxf(xs, 0.0f), (float)(WW - 1));
            int   x0 = (int)floorf(xc);
            float lx = xc - (float)x0;
            float hx = 1.0f - lx;

            // Fused x-pair load; if x0 == 79 then lx == 0, so using the
            // shifted pair (78,79) with t.y for both taps is exact.
            int x0c = min(x0, WW - 2);
            bool shifted = (x0 != x0c);

            f2v t  = *(const f2v*)(plane + y0  * WW + x0c);
            f2v bt = *(const f2v*)(plane + y1i * WW + x0c);

            float v00 = shifted ? t.y  : t.x;
            float v01 = t.y;
            float v10 = shifted ? bt.y : bt.x;
            float v11 = bt.y;

            float vtop = v00 * hx + v01 * lx;
            float vbot = v10 * hx + v11 * lx;
            float v = vtop * hy + vbot * ly;

            if (ymask && xmask) acc += v;
        }
    }

    out[(size_t)n * CIJ + cij] = acc * 0.25f;
}

extern "C" void kernel_launch(void* const* d_in, const int* in_sizes, int n_in,
                              void* d_out, int out_size, void* d_ws, size_t ws_size,
                              hipStream_t stream)
{
    const float* feat = (const float*)d_in[0];
    const float* rois = (const float*)d_in[1];
    float* out = (float*)d_out;

    psroi_align_kernel<<<CIJ, NROI, 0, stream>>>(feat, rois, out);
}

// Round 4
// 115.063 us; speedup vs baseline: 1.2668x; 1.1237x over previous
//
#include <hip/hip_runtime.h>

#define NB   4      // batch
#define CO   16     // out channels
#define PH   7
#define PW   7
#define SR   2
#define HH   80
#define WW   80
#define NROI 512
#define CIJ  (CO*PH*PW)   // 784
#define PLANE (HH*WW)     // 6400 floats = 25.6 KB

typedef float f4v __attribute__((ext_vector_type(4), aligned(4)));

// Grid: 784 blocks, one per (c,i,j). Block: 512 threads, one per ROI.
// Loop over batches: stage plane (b,cij) into LDS with coalesced float4
// streams, then ROIs of that batch gather bilinear taps from LDS.
// Global traffic = feat read exactly once, fully sequential.
__global__ __launch_bounds__(512) void psroi_align_kernel(
    const float* __restrict__ feat,   // [B, CIJ, H, W]
    const float* __restrict__ rois,   // [N, 5]
    float* __restrict__ out)          // [N, CO, PH, PW]
{
    __shared__ float sp[PLANE];       // 25.6 KB -> 4 blocks/CU possible

    int cij = blockIdx.x;
    int rem = cij % (PH * PW);
    int i = rem / PW;
    int j = rem % PW;
    int n = threadIdx.x;

    // --- per-ROI setup (independent of batch loop) ---
    float rb = rois[n * 5 + 0];
    float x1 = rois[n * 5 + 1] * (float)WW;
    float y1 = rois[n * 5 + 2] * (float)HH;
    float x2 = rois[n * 5 + 3] * (float)WW;
    float y2 = rois[n * 5 + 4] * (float)HH;
    int b = (int)rb;

    float roi_h = fmaxf(y2 - y1, 0.1f);
    float roi_w = fmaxf(x2 - x1, 0.1f);
    float bin_h = roi_h * (1.0f / PH);
    float bin_w = roi_w * (1.0f / PW);

    // Precompute y-samples
    int   p0r[SR], p1r[SR];     // row offsets y0*WW, y1i*WW
    float lyv[SR], hyv[SR];
    bool  ymv[SR];
    #pragma unroll
    for (int sy = 0; sy < SR; ++sy) {
        float ys = y1 + (float)i * bin_h + ((float)sy + 0.5f) * bin_h / (float)SR;
        ymv[sy] = (ys >= -1.0f) && (ys <= (float)HH);
        float yc = fminf(fmaxf(ys, 0.0f), (float)(HH - 1));
        int   y0 = (int)floorf(yc);
        int   y1i = min(y0 + 1, HH - 1);
        lyv[sy] = yc - (float)y0;
        hyv[sy] = 1.0f - lyv[sy];
        p0r[sy] = y0 * WW;
        p1r[sy] = y1i * WW;
    }

    // Precompute x-samples
    int   xcv[SR];
    float lxv[SR], hxv[SR];
    bool  xmv[SR], shv[SR];
    #pragma unroll
    for (int sx = 0; sx < SR; ++sx) {
        float xs = x1 + (float)j * bin_w + ((float)sx + 0.5f) * bin_w / (float)SR;
        xmv[sx] = (xs >= -1.0f) && (xs <= (float)WW);
        float xc = fminf(fmaxf(xs, 0.0f), (float)(WW - 1));
        int   x0 = (int)floorf(xc);
        int   x0c = min(x0, WW - 2);      // if x0==79, lx==0 -> shifted pair exact
        shv[sx] = (x0 != x0c);
        lxv[sx] = xc - (float)x0;
        hxv[sx] = 1.0f - lxv[sx];
        xcv[sx] = x0c;
    }

    float acc = 0.0f;

    for (int bb = 0; bb < NB; ++bb) {
        const f4v* src = (const f4v*)(feat + ((size_t)bb * CIJ + (size_t)cij) * PLANE);
        __syncthreads();                  // previous pass's gathers done
        // stage 1600 float4s with 512 threads (3-4 iterations, coalesced)
        #pragma unroll
        for (int it = 0; it < 4; ++it) {
            int e = it * 512 + n;
            if (e < PLANE / 4) ((f4v*)sp)[e] = src[e];
        }
        __syncthreads();

        if (b == bb) {
            #pragma unroll
            for (int sy = 0; sy < SR; ++sy) {
                #pragma unroll
                for (int sx = 0; sx < SR; ++sx) {
                    int p0 = p0r[sy] + xcv[sx];
                    int p1 = p1r[sy] + xcv[sx];
                    float t0 = sp[p0], t1 = sp[p0 + 1];
                    float b0 = sp[p1], b1 = sp[p1 + 1];
                    float v00 = shv[sx] ? t1 : t0;
                    float v10 = shv[sx] ? b1 : b0;
                    float vtop = v00 * hxv[sx] + t1 * lxv[sx];
                    float vbot = v10 * hxv[sx] + b1 * lxv[sx];
                    float v = vtop * hyv[sy] + vbot * lyv[sy];
                    if (ymv[sy] && xmv[sx]) acc += v;
                }
            }
        }
    }

    out[(size_t)n * CIJ + cij] = acc * 0.25f;
}

extern "C" void kernel_launch(void* const* d_in, const int* in_sizes, int n_in,
                              void* d_out, int out_size, void* d_ws, size_t ws_size,
                              hipStream_t stream)
{
    const float* feat = (const float*)d_in[0];
    const float* rois = (const float*)d_in[1];
    float* out = (float*)d_out;

    psroi_align_kernel<<<CIJ, NROI, 0, stream>>>(feat, rois, out);
}

// Round 5
// 114.171 us; speedup vs baseline: 1.2767x; 1.0078x over previous
//
#include <hip/hip_runtime.h>

#define NB   4
#define CO   16
#define PH   7
#define PW   7
#define SR   2
#define HH   80
#define WW   80
#define NROI 512
#define CIJ  (CO*PH*PW)   // 784
#define PLANE (HH*WW)     // 6400 floats = 25.6 KB
#define NF4  (PLANE/4)    // 1600

typedef float f4v __attribute__((ext_vector_type(4), aligned(16)));

// Grid: 784 blocks (one per cij), 512 threads (one per ROI slot).
// Per block: ROIs are compacted by batch into order[] so each batch pass is
// executed by a contiguous (wave-aligned-ish) thread range with full lanes.
// Staging of batch bb+1 is prefetched into registers before the gather of
// batch bb (global latency hidden), then written to the single LDS buffer
// after a barrier. 25.6 KB LDS + launch_bounds(512,8) -> 4 blocks/CU, all
// 784 blocks co-resident.
__global__ __launch_bounds__(512, 8) void psroi_align_kernel(
    const float* __restrict__ feat,   // [B, CIJ, H, W]
    const float* __restrict__ rois,   // [N, 5]
    float* __restrict__ out)          // [N, CO, PH, PW]
{
    __shared__ __align__(16) float sp[PLANE];
    __shared__ unsigned short order[NROI];
    __shared__ int cnt[NB];
    __shared__ int base[NB + 1];

    int cij = blockIdx.x;
    int rem = cij % (PH * PW);
    int i = rem / PW;
    int j = rem % PW;
    int n = threadIdx.x;

    // --- compact ROI indices by batch ---
    if (n < NB) cnt[n] = 0;
    __syncthreads();
    int myb = (int)rois[n * 5 + 0];
    int rank = atomicAdd(&cnt[myb], 1);
    __syncthreads();
    if (n == 0) {
        base[0] = 0;
        for (int k = 0; k < NB; ++k) base[k + 1] = base[k] + cnt[k];
    }
    __syncthreads();
    order[base[myb] + rank] = (unsigned short)n;
    // (covered by the barrier at the top of the batch loop)

    // --- stage batch 0 into LDS ---
    f4v regs[4];
    {
        const f4v* src = (const f4v*)(feat + (size_t)cij * PLANE);
        #pragma unroll
        for (int it = 0; it < 4; ++it) {
            int e = it * 512 + n;
            if (e < NF4) regs[it] = src[e];
        }
        #pragma unroll
        for (int it = 0; it < 4; ++it) {
            int e = it * 512 + n;
            if (e < NF4) ((f4v*)sp)[e] = regs[it];
        }
    }

    for (int bb = 0; bb < NB; ++bb) {
        // prefetch next batch's plane into registers (loads stay in flight
        // during the gather below)
        if (bb + 1 < NB) {
            const f4v* src = (const f4v*)(feat + ((size_t)(bb + 1) * CIJ + cij) * PLANE);
            #pragma unroll
            for (int it = 0; it < 4; ++it) {
                int e = it * 512 + n;
                if (e < NF4) regs[it] = src[e];
            }
        }
        __syncthreads();   // sp holds batch bb (and order[]/base[] visible)

        if (n >= base[bb] && n < base[bb + 1]) {
            int m = order[n];
            float x1 = rois[m * 5 + 1] * (float)WW;
            float y1 = rois[m * 5 + 2] * (float)HH;
            float x2 = rois[m * 5 + 3] * (float)WW;
            float y2 = rois[m * 5 + 4] * (float)HH;
            float bin_h = fmaxf(y2 - y1, 0.1f) * (1.0f / PH);
            float bin_w = fmaxf(x2 - x1, 0.1f) * (1.0f / PW);

            float acc = 0.0f;
            #pragma unroll
            for (int sy = 0; sy < SR; ++sy) {
                float ys = y1 + (float)i * bin_h + ((float)sy + 0.5f) * bin_h / (float)SR;
                bool ymask = (ys >= -1.0f) && (ys <= (float)HH);
                float yc = fminf(fmaxf(ys, 0.0f), (float)(HH - 1));
                int   y0 = (int)floorf(yc);
                int   y1i = min(y0 + 1, HH - 1);
                float ly = yc - (float)y0, hy = 1.0f - ly;
                #pragma unroll
                for (int sx = 0; sx < SR; ++sx) {
                    float xs = x1 + (float)j * bin_w + ((float)sx + 0.5f) * bin_w / (float)SR;
                    bool xmask = (xs >= -1.0f) && (xs <= (float)WW);
                    float xc = fminf(fmaxf(xs, 0.0f), (float)(WW - 1));
                    int   x0 = (int)floorf(xc);
                    int   x0c = min(x0, WW - 2);   // x0==79 -> lx==0, shifted pair exact
                    bool  sh = (x0 != x0c);
                    float lx = xc - (float)x0, hx = 1.0f - lx;

                    float t0 = sp[y0  * WW + x0c], t1 = sp[y0  * WW + x0c + 1];
                    float b0 = sp[y1i * WW + x0c], b1 = sp[y1i * WW + x0c + 1];

                    float v00 = sh ? t1 : t0;
                    float v10 = sh ? b1 : b0;
                    float v = (v00 * hx + t1 * lx) * hy + (v10 * hx + b1 * lx) * ly;
                    if (ymask && xmask) acc += v;
                }
            }
            out[(size_t)m * CIJ + cij] = acc * 0.25f;
        }

        if (bb + 1 < NB) {
            __syncthreads();   // all gathers from sp complete
            #pragma unroll
            for (int it = 0; it < 4; ++it) {
                int e = it * 512 + n;
                if (e < NF4) ((f4v*)sp)[e] = regs[it];
            }
        }
    }
}

extern "C" void kernel_launch(void* const* d_in, const int* in_sizes, int n_in,
                              void* d_out, int out_size, void* d_ws, size_t ws_size,
                              hipStream_t stream)
{
    const float* feat = (const float*)d_in[0];
    const float* rois = (const float*)d_in[1];
    float* out = (float*)d_out;

    psroi_align_kernel<<<CIJ, NROI, 0, stream>>>(feat, rois, out);
}

// Round 6
// 111.270 us; speedup vs baseline: 1.3100x; 1.0261x over previous
//
#include <hip/hip_runtime.h>

#define NB   4
#define CO   16
#define PH   7
#define PW   7
#define SR   2
#define HH   80
#define WW   80
#define NROI 512
#define CIJ  (CO*PH*PW)   // 784
#define PLANE (HH*WW)     // 6400 floats = 25.6 KB
#define NF4  (PLANE/4)    // 1600

typedef float f4v __attribute__((ext_vector_type(4), aligned(16)));

// d_ws layout:
//   [0]    int   base[8]        (prefix offsets per batch, base[4]=512)
//   [64]   u16   order[512]     (roi index, sorted by batch)
//   [2048] f4v   geom[512]      (x1, y1, bin_w, bin_h; indexed by sorted pos)
#define WS_ORDER_OFF 64
#define WS_GEOM_OFF  2048

// ---- pre-kernel: compact ROIs by batch, precompute geometry (1 block) ----
__global__ __launch_bounds__(512) void psroi_prep_kernel(
    const float* __restrict__ rois, int* __restrict__ base,
    unsigned short* __restrict__ order, f4v* __restrict__ geom)
{
    __shared__ int cnt[NB];
    __shared__ int cbase[NB + 1];
    int n = threadIdx.x;
    if (n < NB) cnt[n] = 0;
    __syncthreads();
    int b = (int)rois[n * 5 + 0];
    int rank = atomicAdd(&cnt[b], 1);
    __syncthreads();
    if (n == 0) {
        cbase[0] = 0;
        for (int k = 0; k < NB; ++k) cbase[k + 1] = cbase[k] + cnt[k];
        for (int k = 0; k <= NB; ++k) base[k] = cbase[k];
    }
    __syncthreads();
    int pos = cbase[b] + rank;
    order[pos] = (unsigned short)n;

    float x1 = rois[n * 5 + 1] * (float)WW;
    float y1 = rois[n * 5 + 2] * (float)HH;
    float x2 = rois[n * 5 + 3] * (float)WW;
    float y2 = rois[n * 5 + 4] * (float)HH;
    f4v g;
    g.x = x1;
    g.y = y1;
    g.z = fmaxf(x2 - x1, 0.1f) * (1.0f / PW);   // bin_w
    g.w = fmaxf(y2 - y1, 0.1f) * (1.0f / PH);   // bin_h
    geom[pos] = g;
}

// ---- main kernel: one block per (cij, b) unit ----
// 3136 blocks x 256 threads; stage one 25.6 KB plane to LDS (coalesced f4),
// one barrier, gather that batch's ~128 ROIs from LDS. Global feat traffic
// = 80 MB total (each plane read once). 6 blocks/CU (LDS-capped).
__global__ __launch_bounds__(256) void psroi_main_kernel(
    const float* __restrict__ feat,   // [B, CIJ, H, W]
    const int* __restrict__ base,
    const unsigned short* __restrict__ order,
    const f4v* __restrict__ geom,
    float* __restrict__ out)          // [N, CO, PH, PW]
{
    __shared__ __align__(16) float sp[PLANE];

    int u   = blockIdx.x;       // cij*4 + b
    int cij = u >> 2;
    int b   = u & 3;
    int rem = cij % (PH * PW);
    int i = rem / PW;
    int j = rem % PW;
    int n = threadIdx.x;

    // stage plane (b, cij): 1600 float4s with 256 threads
    const f4v* src = (const f4v*)(feat + ((size_t)b * CIJ + (size_t)cij) * PLANE);
    f4v* dst = (f4v*)sp;
    #pragma unroll
    for (int it = 0; it < 6; ++it)
        dst[it * 256 + n] = src[it * 256 + n];
    {
        int e = 1536 + n;
        if (e < NF4) dst[e] = src[e];
    }

    int lo = base[b];
    int hi = base[b + 1];

    __syncthreads();

    for (int t = lo + n; t < hi; t += 256) {
        int m = (int)order[t];
        f4v g = geom[t];
        float x1 = g.x, y1 = g.y, bin_w = g.z, bin_h = g.w;

        float acc = 0.0f;
        #pragma unroll
        for (int sy = 0; sy < SR; ++sy) {
            float ys = y1 + (float)i * bin_h + ((float)sy + 0.5f) * bin_h / (float)SR;
            bool ymask = (ys >= -1.0f) && (ys <= (float)HH);
            float yc = fminf(fmaxf(ys, 0.0f), (float)(HH - 1));
            int   y0 = (int)floorf(yc);
            int   y1i = min(y0 + 1, HH - 1);
            float ly = yc - (float)y0, hy = 1.0f - ly;
            #pragma unroll
            for (int sx = 0; sx < SR; ++sx) {
                float xs = x1 + (float)j * bin_w + ((float)sx + 0.5f) * bin_w / (float)SR;
                bool xmask = (xs >= -1.0f) && (xs <= (float)WW);
                float xc = fminf(fmaxf(xs, 0.0f), (float)(WW - 1));
                int   x0 = (int)floorf(xc);
                int   x0c = min(x0, WW - 2);   // x0==79 -> lx==0, shifted pair exact
                bool  sh = (x0 != x0c);
                float lx = xc - (float)x0, hx = 1.0f - lx;

                float t0 = sp[y0  * WW + x0c], t1 = sp[y0  * WW + x0c + 1];
                float b0 = sp[y1i * WW + x0c], b1 = sp[y1i * WW + x0c + 1];

                float v00 = sh ? t1 : t0;
                float v10 = sh ? b1 : b0;
                float v = (v00 * hx + t1 * lx) * hy + (v10 * hx + b1 * lx) * ly;
                if (ymask && xmask) acc += v;
            }
        }
        out[(size_t)m * CIJ + cij] = acc * 0.25f;
    }
}

extern "C" void kernel_launch(void* const* d_in, const int* in_sizes, int n_in,
                              void* d_out, int out_size, void* d_ws, size_t ws_size,
                              hipStream_t stream)
{
    const float* feat = (const float*)d_in[0];
    const float* rois = (const float*)d_in[1];
    float* out = (float*)d_out;

    char* ws = (char*)d_ws;
    int* base = (int*)ws;
    unsigned short* order = (unsigned short*)(ws + WS_ORDER_OFF);
    f4v* geom = (f4v*)(ws + WS_GEOM_OFF);

    psroi_prep_kernel<<<1, NROI, 0, stream>>>(rois, base, order, geom);
    psroi_main_kernel<<<CIJ * NB, 256, 0, stream>>>(feat, base, order, geom, out);
}